// Round 2
// baseline (508.170 us; speedup 1.0000x reference)
//
#include <hip/hip_runtime.h>

// ---------------------------------------------------------------------------
// EdgeModel: out = LayerNorm(LReLU(LReLU(LReLU(X@W1+b1)@W2+b2)@W3+b3))
// X = concat[src, dest, edge_attr, u[batch]]  (E=400000, 512 features)
// R2: M_TILE=64, 4 waves, 40KB LDS -> 3-4 blocks/CU (was 1). T14 prefetch in L1.
// ---------------------------------------------------------------------------

typedef short bf16x8 __attribute__((ext_vector_type(8)));   // 8 bf16 (guide §3)
typedef float f32x4 __attribute__((ext_vector_type(4)));
typedef unsigned short us4 __attribute__((ext_vector_type(4)));

__device__ __forceinline__ unsigned short f2bf(float f) {  // RNE f32->bf16
    union { float f; unsigned u; } v; v.f = f;
    return (unsigned short)((v.u + 0x7fffu + ((v.u >> 16) & 1u)) >> 16);
}
__device__ __forceinline__ float lrelu(float v) { return v >= 0.f ? v : 0.01f * v; }

// ---------------------------------------------------------------------------
// Pack W (K x N, row-major f32) into bf16 MFMA-B-fragment order:
// frag(fk,fn): lane l, elem j  ->  W[fk*32 + (l>>4)*8 + j][fn*16 + (l&15)]
// offset(elems) = ((fk*nfn + fn)*64 + l)*8 + j
// ---------------------------------------------------------------------------
__global__ void prep_pack(const float* __restrict__ W1, const float* __restrict__ W2,
                          const float* __restrict__ W3, unsigned short* __restrict__ P) {
    int idx = blockIdx.x * 256 + threadIdx.x;
    const float* W; int N, base;
    if (idx < 131072)      { W = W1; N = 256; base = 0; }
    else if (idx < 196608) { W = W2; N = 256; base = 131072; }
    else if (idx < 229376) { W = W3; N = 128; base = 196608; }
    else return;
    int t = idx - base;
    int j = t & 7, l = (t >> 3) & 63, f = t >> 9;
    int nfn = N >> 4;
    int fk = f / nfn, fn = f - fk * nfn;
    int k = fk * 32 + ((l >> 4) << 3) + j;
    int c = fn * 16 + (l & 15);
    P[idx] = f2bf(W[k * N + c]);
}

// ---------------------------------------------------------------------------
// Main fused kernel. Block = 256 threads (4 waves, 1M x 4N), M_TILE = 64.
// LDS: xs 8KB (64x64 bf16 K-slice, swizzled) + hs 32KB (64x256 bf16, reused
// as 64x128 f32 for LN) = 40KB -> 3-4 blocks/CU.
// ---------------------------------------------------------------------------
__global__ __launch_bounds__(256, 4) void edge_mlp(
    const float* __restrict__ src, const float* __restrict__ dst,
    const float* __restrict__ ea,  const float* __restrict__ u,
    const int* __restrict__ batch, const unsigned short* __restrict__ Wp,
    const float* __restrict__ b1,  const float* __restrict__ b2,
    const float* __restrict__ b3,  const float* __restrict__ gamma,
    const float* __restrict__ beta, float* __restrict__ out, int E)
{
    __shared__ __align__(16) unsigned char xs[64 * 128];
    __shared__ __align__(16) unsigned char hs[64 * 512];

    const int tid  = threadIdx.x;
    const int lane = tid & 63;
    const int wn   = tid >> 6;          // wave 0..3 = N quarter
    const int l15  = lane & 15;
    const int lhi  = lane >> 4;         // 0..3
    const int m0   = blockIdx.x * 64;

    const unsigned short* W1p = Wp;
    const unsigned short* W2p = Wp + 131072;
    const unsigned short* W3p = Wp + 196608;

    const f32x4 zero4 = {0.f, 0.f, 0.f, 0.f};
    f32x4 acc[4][4];
    #pragma unroll
    for (int m = 0; m < 4; ++m)
        #pragma unroll
        for (int n = 0; n < 4; ++n) acc[m][n] = zero4;

    // ============================ layer 1 (K=512) ===========================
    // T14 prefetch: slice ks+1's global loads issued right after the read
    // barrier, consumed (LDS-written) next iteration -> latency under MFMA.
    f32x4 pf[4];
    const int ldr = tid >> 4;           // 0..15 (row within 16-row group)
    const int ldc = tid & 15;           // f32x4 column in 64-col slice
    {   // load slice 0 (seg 0 = src, cols 0..63)
        #pragma unroll
        for (int p = 0; p < 4; ++p) {
            int rg = m0 + p * 16 + ldr; rg = rg < E ? rg : E - 1;
            pf[p] = *reinterpret_cast<const f32x4*>(src + (size_t)rg * 128 + ldc * 4);
        }
    }
    for (int ks = 0; ks < 8; ++ks) {
        // write prefetched slice -> xs (bf16, swizzled)
        #pragma unroll
        for (int p = 0; p < 4; ++p) {
            int r = p * 16 + ldr;
            us4 h; h.x = f2bf(pf[p].x); h.y = f2bf(pf[p].y);
                   h.z = f2bf(pf[p].z); h.w = f2bf(pf[p].w);
            *reinterpret_cast<us4*>(&xs[r * 128 + ((ldc * 8) ^ ((r & 7) << 4))]) = h;
        }
        __syncthreads();
        if (ks < 7) {   // issue next slice's loads (overlap with MFMA below)
            const int ksn = ks + 1;
            const int seg = ksn >> 1;            // 0:src 1:dst 2:ea 3:u[batch]
            const int sc  = (ksn & 1) << 6;
            const float* bp = (seg == 0) ? src : (seg == 1) ? dst : ea;
            #pragma unroll
            for (int p = 0; p < 4; ++p) {
                int rg = m0 + p * 16 + ldr; rg = rg < E ? rg : E - 1;
                const float* gp = (seg == 3)
                    ? u  + (size_t)batch[rg] * 128 + sc + ldc * 4
                    : bp + (size_t)rg       * 128 + sc + ldc * 4;
                pf[p] = *reinterpret_cast<const f32x4*>(gp);
            }
        }
        #pragma unroll
        for (int kk = 0; kk < 2; ++kk) {       // two K=32 steps per slice
            const int klo = kk * 32 + lhi * 8;
            bf16x8 a[4], b[4];
            #pragma unroll
            for (int m = 0; m < 4; ++m) {
                int r = m * 16 + l15;
                a[m] = *reinterpret_cast<const bf16x8*>(
                    &xs[r * 128 + ((klo * 2) ^ ((r & 7) << 4))]);
            }
            const int fk = ks * 2 + kk;
            #pragma unroll
            for (int n = 0; n < 4; ++n) {
                int fn = wn * 4 + n;
                b[n] = *reinterpret_cast<const bf16x8*>(
                    W1p + (((fk * 16 + fn) << 6) + lane) * 8);
            }
            #pragma unroll
            for (int m = 0; m < 4; ++m)
                #pragma unroll
                for (int n = 0; n < 4; ++n)
                    acc[m][n] = __builtin_amdgcn_mfma_f32_16x16x32_bf16(
                        a[m], b[n], acc[m][n], 0, 0, 0);
        }
        __syncthreads();   // xs consumed; safe to overwrite next iter
    }
    // h1 = LReLU(acc + b1) -> hs (bf16, swizzled). hs first use: no barrier.
    #pragma unroll
    for (int n = 0; n < 4; ++n) {
        int col = wn * 64 + n * 16 + l15;
        float bias = b1[col];
        #pragma unroll
        for (int m = 0; m < 4; ++m)
            #pragma unroll
            for (int r = 0; r < 4; ++r) {
                int row = m * 16 + lhi * 4 + r;
                float v = lrelu(acc[m][n][r] + bias);
                *reinterpret_cast<unsigned short*>(
                    &hs[row * 512 + ((col * 2) ^ ((row & 7) << 4))]) = f2bf(v);
            }
    }
    __syncthreads();

    // ============================ layer 2 (K=256) ===========================
    #pragma unroll
    for (int m = 0; m < 4; ++m)
        #pragma unroll
        for (int n = 0; n < 4; ++n) acc[m][n] = zero4;
    for (int kk = 0; kk < 8; ++kk) {
        const int k = kk * 32 + lhi * 8;
        bf16x8 a[4], b[4];
        #pragma unroll
        for (int m = 0; m < 4; ++m) {
            int r = m * 16 + l15;
            a[m] = *reinterpret_cast<const bf16x8*>(
                &hs[r * 512 + ((k * 2) ^ ((r & 7) << 4))]);
        }
        #pragma unroll
        for (int n = 0; n < 4; ++n) {
            int fn = wn * 4 + n;
            b[n] = *reinterpret_cast<const bf16x8*>(
                W2p + (((kk * 16 + fn) << 6) + lane) * 8);
        }
        #pragma unroll
        for (int m = 0; m < 4; ++m)
            #pragma unroll
            for (int n = 0; n < 4; ++n)
                acc[m][n] = __builtin_amdgcn_mfma_f32_16x16x32_bf16(
                    a[m], b[n], acc[m][n], 0, 0, 0);
    }
    __syncthreads();   // all reads of h1 done before overwrite
    #pragma unroll
    for (int n = 0; n < 4; ++n) {
        int col = wn * 64 + n * 16 + l15;
        float bias = b2[col];
        #pragma unroll
        for (int m = 0; m < 4; ++m)
            #pragma unroll
            for (int r = 0; r < 4; ++r) {
                int row = m * 16 + lhi * 4 + r;
                float v = lrelu(acc[m][n][r] + bias);
                *reinterpret_cast<unsigned short*>(
                    &hs[row * 512 + ((col * 2) ^ ((row & 7) << 4))]) = f2bf(v);
            }
    }
    __syncthreads();

    // ============================ layer 3 (K=256, N=128) ====================
    f32x4 acc3[4][2];
    #pragma unroll
    for (int m = 0; m < 4; ++m) { acc3[m][0] = zero4; acc3[m][1] = zero4; }
    for (int kk = 0; kk < 8; ++kk) {
        const int k = kk * 32 + lhi * 8;
        bf16x8 a[4], b[2];
        #pragma unroll
        for (int m = 0; m < 4; ++m) {
            int r = m * 16 + l15;
            a[m] = *reinterpret_cast<const bf16x8*>(
                &hs[r * 512 + ((k * 2) ^ ((r & 7) << 4))]);
        }
        #pragma unroll
        for (int n = 0; n < 2; ++n) {
            int fn = wn * 2 + n;
            b[n] = *reinterpret_cast<const bf16x8*>(
                W3p + (((kk * 8 + fn) << 6) + lane) * 8);
        }
        #pragma unroll
        for (int m = 0; m < 4; ++m)
            #pragma unroll
            for (int n = 0; n < 2; ++n)
                acc3[m][n] = __builtin_amdgcn_mfma_f32_16x16x32_bf16(
                    a[m], b[n], acc3[m][n], 0, 0, 0);
    }
    __syncthreads();   // all reads of h2 done before f32 overwrite
    #pragma unroll
    for (int n = 0; n < 2; ++n) {
        int col = wn * 32 + n * 16 + l15;
        float bias = b3[col];
        #pragma unroll
        for (int m = 0; m < 4; ++m)
            #pragma unroll
            for (int r = 0; r < 4; ++r) {
                int row = m * 16 + lhi * 4 + r;
                float v = lrelu(acc3[m][n][r] + bias);
                *reinterpret_cast<float*>(
                    &hs[row * 512 + ((col * 4) ^ ((row & 7) << 4))]) = v;
            }
    }
    __syncthreads();

    // ====================== LayerNorm(128) + store ==========================
    {
        const int row = tid >> 2;   // 0..63
        const int sub = tid & 3;    // 4 lanes per row
        f32x4 vv[8];
        float s = 0.f, s2 = 0.f;
        #pragma unroll
        for (int j = 0; j < 8; ++j) {
            int cb = j * 16 + sub * 4;
            f32x4 t = *reinterpret_cast<const f32x4*>(
                &hs[row * 512 + ((cb * 4) ^ ((row & 7) << 4))]);
            vv[j] = t;
            s  += t.x + t.y + t.z + t.w;
            s2 += t.x * t.x + t.y * t.y + t.z * t.z + t.w * t.w;
        }
        s  += __shfl_xor(s, 1);  s  += __shfl_xor(s, 2);
        s2 += __shfl_xor(s2, 1); s2 += __shfl_xor(s2, 2);
        const float mean = s * (1.f / 128.f);
        const float var  = s2 * (1.f / 128.f) - mean * mean;
        const float rstd = rsqrtf(var + 1e-5f);
        const int rg = m0 + row;
        if (rg < E) {
            float* op = out + (size_t)rg * 128;
            #pragma unroll
            for (int j = 0; j < 8; ++j) {
                int cb = j * 16 + sub * 4;
                f32x4 g  = *reinterpret_cast<const f32x4*>(gamma + cb);
                f32x4 be = *reinterpret_cast<const f32x4*>(beta + cb);
                f32x4 o;
                o.x = (vv[j].x - mean) * rstd * g.x + be.x;
                o.y = (vv[j].y - mean) * rstd * g.y + be.y;
                o.z = (vv[j].z - mean) * rstd * g.z + be.z;
                o.w = (vv[j].w - mean) * rstd * g.w + be.w;
                *reinterpret_cast<f32x4*>(op + cb) = o;
            }
        }
    }
}

extern "C" void kernel_launch(void* const* d_in, const int* in_sizes, int n_in,
                              void* d_out, int out_size, void* d_ws, size_t ws_size,
                              hipStream_t stream) {
    const float* src  = (const float*)d_in[0];
    const float* dst  = (const float*)d_in[1];
    const float* ea   = (const float*)d_in[2];
    const float* u    = (const float*)d_in[3];
    const int*   bat  = (const int*)d_in[4];
    const float* W1   = (const float*)d_in[5];
    const float* b1   = (const float*)d_in[6];
    const float* W2   = (const float*)d_in[7];
    const float* b2   = (const float*)d_in[8];
    const float* W3   = (const float*)d_in[9];
    const float* b3   = (const float*)d_in[10];
    const float* gam  = (const float*)d_in[11];
    const float* bet  = (const float*)d_in[12];
    float* out = (float*)d_out;
    unsigned short* Wp = (unsigned short*)d_ws;   // 458752 B used

    const int E = in_sizes[0] / 128;

    prep_pack<<<896, 256, 0, stream>>>(W1, W2, W3, Wp);
    const int nblk = (E + 63) / 64;
    edge_mlp<<<nblk, 256, 0, stream>>>(src, dst, ea, u, bat, Wp,
                                       b1, b2, b3, gam, bet, out, E);
}

// Round 3
// 362.492 us; speedup vs baseline: 1.4019x; 1.4019x over previous
//
#include <hip/hip_runtime.h>

// ---------------------------------------------------------------------------
// EdgeModel: out = LayerNorm(LReLU(LReLU(LReLU(X@W1+b1)@W2+b2)@W3+b3))
// X = concat[src, dest, edge_attr, u[batch]]  (E=400000, 512 features)
// R3: drop min-waves hint (R2's __launch_bounds__(256,4) capped VGPR at 64 ->
//     acc spilled -> +800MB scratch HBM traffic). Double-buffered xs, one
//     barrier per K-slice. 48KB LDS, ~3 blocks/CU (VGPR-limited).
// ---------------------------------------------------------------------------

typedef short bf16x8 __attribute__((ext_vector_type(8)));   // 8 bf16 (guide §3)
typedef float f32x4 __attribute__((ext_vector_type(4)));
typedef unsigned short us4 __attribute__((ext_vector_type(4)));

__device__ __forceinline__ unsigned short f2bf(float f) {  // RNE f32->bf16
    union { float f; unsigned u; } v; v.f = f;
    return (unsigned short)((v.u + 0x7fffu + ((v.u >> 16) & 1u)) >> 16);
}
__device__ __forceinline__ float lrelu(float v) { return v >= 0.f ? v : 0.01f * v; }

// ---------------------------------------------------------------------------
// Pack W (K x N, row-major f32) into bf16 MFMA-B-fragment order:
// frag(fk,fn): lane l, elem j  ->  W[fk*32 + (l>>4)*8 + j][fn*16 + (l&15)]
// offset(elems) = ((fk*nfn + fn)*64 + l)*8 + j
// ---------------------------------------------------------------------------
__global__ void prep_pack(const float* __restrict__ W1, const float* __restrict__ W2,
                          const float* __restrict__ W3, unsigned short* __restrict__ P) {
    int idx = blockIdx.x * 256 + threadIdx.x;
    const float* W; int N, base;
    if (idx < 131072)      { W = W1; N = 256; base = 0; }
    else if (idx < 196608) { W = W2; N = 256; base = 131072; }
    else if (idx < 229376) { W = W3; N = 128; base = 196608; }
    else return;
    int t = idx - base;
    int j = t & 7, l = (t >> 3) & 63, f = t >> 9;
    int nfn = N >> 4;
    int fk = f / nfn, fn = f - fk * nfn;
    int k = fk * 32 + ((l >> 4) << 3) + j;
    int c = fn * 16 + (l & 15);
    P[idx] = f2bf(W[k * N + c]);
}

// ---------------------------------------------------------------------------
// Main fused kernel. Block = 256 threads (4 waves, 1M x 4N), M_TILE = 64.
// LDS: xs 2x8KB (double-buffered 64x64 bf16 K-slice, swizzled)
//    + hs 32KB (64x256 bf16 activations, reused as 64x128 f32 for LN) = 48KB.
// NOTE: no min-waves in launch_bounds — (256,4) forces VGPR<=128 incl AGPRs
// and spills acc (R2: +500MB HBM writes). Let allocator pick (~164 total).
// ---------------------------------------------------------------------------
__global__ __launch_bounds__(256) void edge_mlp(
    const float* __restrict__ src, const float* __restrict__ dst,
    const float* __restrict__ ea,  const float* __restrict__ u,
    const int* __restrict__ batch, const unsigned short* __restrict__ Wp,
    const float* __restrict__ b1,  const float* __restrict__ b2,
    const float* __restrict__ b3,  const float* __restrict__ gamma,
    const float* __restrict__ beta, float* __restrict__ out, int E)
{
    __shared__ __align__(16) unsigned char xs[2][64 * 128];
    __shared__ __align__(16) unsigned char hs[64 * 512];

    const int tid  = threadIdx.x;
    const int lane = tid & 63;
    const int wn   = tid >> 6;          // wave 0..3 = N quarter
    const int l15  = lane & 15;
    const int lhi  = lane >> 4;         // 0..3
    const int m0   = blockIdx.x * 64;

    const unsigned short* W1p = Wp;
    const unsigned short* W2p = Wp + 131072;
    const unsigned short* W3p = Wp + 196608;

    const f32x4 zero4 = {0.f, 0.f, 0.f, 0.f};
    f32x4 acc[4][4];
    #pragma unroll
    for (int m = 0; m < 4; ++m)
        #pragma unroll
        for (int n = 0; n < 4; ++n) acc[m][n] = zero4;

    // ============================ layer 1 (K=512) ===========================
    // Double-buffered xs; per slice: issue next loads -> MFMA(cur) -> write
    // next buffer -> ONE barrier. Load latency hides under MFMA phase.
    f32x4 pf[4];
    const int ldr = tid >> 4;           // 0..15 (row within 16-row group)
    const int ldc = tid & 15;           // f32x4 column in 64-col slice
    {   // prologue: slice 0 (seg 0 = src, cols 0..63) -> xs[0]
        #pragma unroll
        for (int p = 0; p < 4; ++p) {
            int rg = m0 + p * 16 + ldr; rg = rg < E ? rg : E - 1;
            pf[p] = *reinterpret_cast<const f32x4*>(src + (size_t)rg * 128 + ldc * 4);
        }
        #pragma unroll
        for (int p = 0; p < 4; ++p) {
            int r = p * 16 + ldr;
            us4 h; h.x = f2bf(pf[p].x); h.y = f2bf(pf[p].y);
                   h.z = f2bf(pf[p].z); h.w = f2bf(pf[p].w);
            *reinterpret_cast<us4*>(&xs[0][r * 128 + ((ldc * 8) ^ ((r & 7) << 4))]) = h;
        }
        __syncthreads();
    }
    for (int ks = 0; ks < 8; ++ks) {
        const int cur = ks & 1;
        if (ks < 7) {   // issue next slice's global loads (consumed post-MFMA)
            const int ksn = ks + 1;
            const int seg = ksn >> 1;            // 0:src 1:dst 2:ea 3:u[batch]
            const int sc  = (ksn & 1) << 6;
            const float* bp = (seg == 0) ? src : (seg == 1) ? dst : ea;
            #pragma unroll
            for (int p = 0; p < 4; ++p) {
                int rg = m0 + p * 16 + ldr; rg = rg < E ? rg : E - 1;
                const float* gp = (seg == 3)
                    ? u  + (size_t)batch[rg] * 128 + sc + ldc * 4
                    : bp + (size_t)rg       * 128 + sc + ldc * 4;
                pf[p] = *reinterpret_cast<const f32x4*>(gp);
            }
        }
        #pragma unroll
        for (int kk = 0; kk < 2; ++kk) {       // two K=32 steps per slice
            const int klo = kk * 32 + lhi * 8;
            bf16x8 a[4], b[4];
            #pragma unroll
            for (int m = 0; m < 4; ++m) {
                int r = m * 16 + l15;
                a[m] = *reinterpret_cast<const bf16x8*>(
                    &xs[cur][r * 128 + ((klo * 2) ^ ((r & 7) << 4))]);
            }
            const int fk = ks * 2 + kk;
            #pragma unroll
            for (int n = 0; n < 4; ++n) {
                int fn = wn * 4 + n;
                b[n] = *reinterpret_cast<const bf16x8*>(
                    W1p + (((fk * 16 + fn) << 6) + lane) * 8);
            }
            #pragma unroll
            for (int m = 0; m < 4; ++m)
                #pragma unroll
                for (int n = 0; n < 4; ++n)
                    acc[m][n] = __builtin_amdgcn_mfma_f32_16x16x32_bf16(
                        a[m], b[n], acc[m][n], 0, 0, 0);
        }
        if (ks < 7) {   // write prefetched slice into the other buffer
            #pragma unroll
            for (int p = 0; p < 4; ++p) {
                int r = p * 16 + ldr;
                us4 h; h.x = f2bf(pf[p].x); h.y = f2bf(pf[p].y);
                       h.z = f2bf(pf[p].z); h.w = f2bf(pf[p].w);
                *reinterpret_cast<us4*>(
                    &xs[cur ^ 1][r * 128 + ((ldc * 8) ^ ((r & 7) << 4))]) = h;
            }
        }
        __syncthreads();   // next buffer ready; cur fully consumed by all waves
    }
    // h1 = LReLU(acc + b1) -> hs (bf16, swizzled). hs first use: no barrier.
    #pragma unroll
    for (int n = 0; n < 4; ++n) {
        int col = wn * 64 + n * 16 + l15;
        float bias = b1[col];
        #pragma unroll
        for (int m = 0; m < 4; ++m)
            #pragma unroll
            for (int r = 0; r < 4; ++r) {
                int row = m * 16 + lhi * 4 + r;
                float v = lrelu(acc[m][n][r] + bias);
                *reinterpret_cast<unsigned short*>(
                    &hs[row * 512 + ((col * 2) ^ ((row & 7) << 4))]) = f2bf(v);
            }
    }
    __syncthreads();

    // ============================ layer 2 (K=256) ===========================
    #pragma unroll
    for (int m = 0; m < 4; ++m)
        #pragma unroll
        for (int n = 0; n < 4; ++n) acc[m][n] = zero4;
    for (int kk = 0; kk < 8; ++kk) {
        const int k = kk * 32 + lhi * 8;
        bf16x8 a[4], b[4];
        #pragma unroll
        for (int m = 0; m < 4; ++m) {
            int r = m * 16 + l15;
            a[m] = *reinterpret_cast<const bf16x8*>(
                &hs[r * 512 + ((k * 2) ^ ((r & 7) << 4))]);
        }
        #pragma unroll
        for (int n = 0; n < 4; ++n) {
            int fn = wn * 4 + n;
            b[n] = *reinterpret_cast<const bf16x8*>(
                W2p + (((kk * 16 + fn) << 6) + lane) * 8);
        }
        #pragma unroll
        for (int m = 0; m < 4; ++m)
            #pragma unroll
            for (int n = 0; n < 4; ++n)
                acc[m][n] = __builtin_amdgcn_mfma_f32_16x16x32_bf16(
                    a[m], b[n], acc[m][n], 0, 0, 0);
    }
    __syncthreads();   // all reads of h1 done before overwrite
    #pragma unroll
    for (int n = 0; n < 4; ++n) {
        int col = wn * 64 + n * 16 + l15;
        float bias = b2[col];
        #pragma unroll
        for (int m = 0; m < 4; ++m)
            #pragma unroll
            for (int r = 0; r < 4; ++r) {
                int row = m * 16 + lhi * 4 + r;
                float v = lrelu(acc[m][n][r] + bias);
                *reinterpret_cast<unsigned short*>(
                    &hs[row * 512 + ((col * 2) ^ ((row & 7) << 4))]) = f2bf(v);
            }
    }
    __syncthreads();

    // ============================ layer 3 (K=256, N=128) ====================
    f32x4 acc3[4][2];
    #pragma unroll
    for (int m = 0; m < 4; ++m) { acc3[m][0] = zero4; acc3[m][1] = zero4; }
    for (int kk = 0; kk < 8; ++kk) {
        const int k = kk * 32 + lhi * 8;
        bf16x8 a[4], b[2];
        #pragma unroll
        for (int m = 0; m < 4; ++m) {
            int r = m * 16 + l15;
            a[m] = *reinterpret_cast<const bf16x8*>(
                &hs[r * 512 + ((k * 2) ^ ((r & 7) << 4))]);
        }
        #pragma unroll
        for (int n = 0; n < 2; ++n) {
            int fn = wn * 2 + n;
            b[n] = *reinterpret_cast<const bf16x8*>(
                W3p + (((kk * 8 + fn) << 6) + lane) * 8);
        }
        #pragma unroll
        for (int m = 0; m < 4; ++m)
            #pragma unroll
            for (int n = 0; n < 2; ++n)
                acc3[m][n] = __builtin_amdgcn_mfma_f32_16x16x32_bf16(
                    a[m], b[n], acc3[m][n], 0, 0, 0);
    }
    __syncthreads();   // all reads of h2 done before f32 overwrite
    #pragma unroll
    for (int n = 0; n < 2; ++n) {
        int col = wn * 32 + n * 16 + l15;
        float bias = b3[col];
        #pragma unroll
        for (int m = 0; m < 4; ++m)
            #pragma unroll
            for (int r = 0; r < 4; ++r) {
                int row = m * 16 + lhi * 4 + r;
                float v = lrelu(acc3[m][n][r] + bias);
                *reinterpret_cast<float*>(
                    &hs[row * 512 + ((col * 4) ^ ((row & 7) << 4))]) = v;
            }
    }
    __syncthreads();

    // ====================== LayerNorm(128) + store ==========================
    {
        const int row = tid >> 2;   // 0..63
        const int sub = tid & 3;    // 4 lanes per row
        f32x4 vv[8];
        float s = 0.f, s2 = 0.f;
        #pragma unroll
        for (int j = 0; j < 8; ++j) {
            int cb = j * 16 + sub * 4;
            f32x4 t = *reinterpret_cast<const f32x4*>(
                &hs[row * 512 + ((cb * 4) ^ ((row & 7) << 4))]);
            vv[j] = t;
            s  += t.x + t.y + t.z + t.w;
            s2 += t.x * t.x + t.y * t.y + t.z * t.z + t.w * t.w;
        }
        s  += __shfl_xor(s, 1);  s  += __shfl_xor(s, 2);
        s2 += __shfl_xor(s2, 1); s2 += __shfl_xor(s2, 2);
        const float mean = s * (1.f / 128.f);
        const float var  = s2 * (1.f / 128.f) - mean * mean;
        const float rstd = rsqrtf(var + 1e-5f);
        const int rg = m0 + row;
        if (rg < E) {
            float* op = out + (size_t)rg * 128;
            #pragma unroll
            for (int j = 0; j < 8; ++j) {
                int cb = j * 16 + sub * 4;
                f32x4 g  = *reinterpret_cast<const f32x4*>(gamma + cb);
                f32x4 be = *reinterpret_cast<const f32x4*>(beta + cb);
                f32x4 o;
                o.x = (vv[j].x - mean) * rstd * g.x + be.x;
                o.y = (vv[j].y - mean) * rstd * g.y + be.y;
                o.z = (vv[j].z - mean) * rstd * g.z + be.z;
                o.w = (vv[j].w - mean) * rstd * g.w + be.w;
                *reinterpret_cast<f32x4*>(op + cb) = o;
            }
        }
    }
}

extern "C" void kernel_launch(void* const* d_in, const int* in_sizes, int n_in,
                              void* d_out, int out_size, void* d_ws, size_t ws_size,
                              hipStream_t stream) {
    const float* src  = (const float*)d_in[0];
    const float* dst  = (const float*)d_in[1];
    const float* ea   = (const float*)d_in[2];
    const float* u    = (const float*)d_in[3];
    const int*   bat  = (const int*)d_in[4];
    const float* W1   = (const float*)d_in[5];
    const float* b1   = (const float*)d_in[6];
    const float* W2   = (const float*)d_in[7];
    const float* b2   = (const float*)d_in[8];
    const float* W3   = (const float*)d_in[9];
    const float* b3   = (const float*)d_in[10];
    const float* gam  = (const float*)d_in[11];
    const float* bet  = (const float*)d_in[12];
    float* out = (float*)d_out;
    unsigned short* Wp = (unsigned short*)d_ws;   // 458752 B used

    const int E = in_sizes[0] / 128;

    prep_pack<<<896, 256, 0, stream>>>(W1, W2, W3, Wp);
    const int nblk = (E + 63) / 64;
    edge_mlp<<<nblk, 256, 0, stream>>>(src, dst, ea, u, bat, Wp,
                                       b1, b2, b3, gam, bet, out, E);
}